// Round 1
// baseline (796.344 us; speedup 1.0000x reference)
//
#include <hip/hip_runtime.h>

#define NTOK 8192
#define DMODEL 512

typedef _Float16 f16;
typedef _Float16 f16x4 __attribute__((ext_vector_type(4)));
typedef _Float16 f16x8 __attribute__((ext_vector_type(8)));
typedef float f32x4 __attribute__((ext_vector_type(4)));

// async global->LDS, 16B per lane; lds dest = wave-uniform base + lane*16
__device__ __forceinline__ void async_ld16(const void* g, void* l) {
  __builtin_amdgcn_global_load_lds((const __attribute__((address_space(1))) void*)g,
                                   (__attribute__((address_space(3))) void*)l, 16, 0, 0);
}

// ---------------- pack fp32 -> f16 (elementwise, float4 vectorized) ----------------
__global__ void pack_f16(const float* __restrict__ s, f16* __restrict__ d, int n) {
  int i = (blockIdx.x * 256 + threadIdx.x) * 4;
  if (i >= n) return;
  float4 v = *(const float4*)(s + i);
  f16x4 h; h.x = (f16)v.x; h.y = (f16)v.y; h.z = (f16)v.z; h.w = (f16)v.w;
  *(f16x4*)(d + i) = h;
}

// ---------------- transpose V [NTOK][D] -> Vt [D][NTOK] ----------------
__global__ __launch_bounds__(256) void transpose_f16(const f16* __restrict__ src,
                                                     f16* __restrict__ dst) {
  __shared__ f16 T[64][72];  // +8 pad breaks bank alignment
  int t = threadIdx.x;
  int tok0 = blockIdx.x * 64, d0 = blockIdx.y * 64;
#pragma unroll
  for (int i = 0; i < 2; ++i) {
    int row = (t >> 3) + i * 32;
    int col = (t & 7) * 8;
    f16x8 v = *(const f16x8*)(src + (size_t)(tok0 + row) * DMODEL + d0 + col);
    *(f16x8*)(&T[row][col]) = v;
  }
  __syncthreads();
#pragma unroll
  for (int i = 0; i < 2; ++i) {
    int od = (t >> 3) + i * 32;  // d within tile
    int ot = (t & 7) * 8;        // token within tile
    f16x8 v;
#pragma unroll
    for (int j = 0; j < 8; ++j) v[j] = T[ot + j][od];
    *(f16x8*)(dst + (size_t)(d0 + od) * NTOK + tok0 + ot) = v;
  }
}

// stage 128x32 f16 tile from row-major G (row stride rs halfs) at (r0,k0) into lds
__device__ __forceinline__ void stage128x32(const f16* G, int r0, int k0, int rs,
                                            f16* lds, int t) {
  int wv = t >> 6;
  const f16* g0 = G + (size_t)(r0 + (t >> 2)) * rs + k0 + (t & 3) * 8;
  async_ld16(g0, (char*)lds + wv * 1024);
  const f16* g1 = g0 + (size_t)64 * rs;
  async_ld16(g1, (char*)lds + 4096 + wv * 1024);
}

// ---------------- QKV: C[i,j] = sum_k X[i,k] * W[j,k]  (gemm_bt) ----------------
__global__ __launch_bounds__(256) void qkv_gemm(const f16* __restrict__ X,
                                                const f16* __restrict__ Wall,
                                                f16* __restrict__ Out) {
  __shared__ f16 As[128 * 32];
  __shared__ f16 Bs[128 * 32];
  int t = threadIdx.x;
  int z = blockIdx.z;
  const f16* B = Wall + (size_t)z * DMODEL * DMODEL;
  f16* C = Out + (size_t)z * NTOK * DMODEL;
  int m0 = blockIdx.y * 128, n0 = blockIdx.x * 128;
  int lane = t & 63, wv = t >> 6, quad = lane >> 4, l15 = lane & 15;
  int m_off = (wv & 1) * 64, n_off = (wv >> 1) * 64;
  f32x4 acc[4][4] = {};
  for (int kt = 0; kt < DMODEL; kt += 32) {
    __syncthreads();
    stage128x32(X, m0, kt, DMODEL, As, t);
    stage128x32(B, n0, kt, DMODEL, Bs, t);
    __syncthreads();
    f16x8 af[4], bf[4];
    const f16x8* Av = (const f16x8*)As;
    const f16x8* Bv = (const f16x8*)Bs;
#pragma unroll
    for (int mt = 0; mt < 4; ++mt) af[mt] = Av[(m_off + mt * 16 + l15) * 4 + quad];
#pragma unroll
    for (int nt = 0; nt < 4; ++nt) bf[nt] = Bv[(n_off + nt * 16 + l15) * 4 + quad];
#pragma unroll
    for (int mt = 0; mt < 4; ++mt)
#pragma unroll
      for (int nt = 0; nt < 4; ++nt)
        acc[mt][nt] = __builtin_amdgcn_mfma_f32_16x16x32_f16(af[mt], bf[nt], acc[mt][nt], 0, 0, 0);
  }
#pragma unroll
  for (int mt = 0; mt < 4; ++mt)
#pragma unroll
    for (int nt = 0; nt < 4; ++nt)
#pragma unroll
      for (int r = 0; r < 4; ++r) {
        int row = m0 + m_off + mt * 16 + quad * 4 + r;
        int col = n0 + n_off + nt * 16 + l15;
        C[(size_t)row * DMODEL + col] = (f16)acc[mt][nt][r];
      }
}

// ------- scores: E = exp(mask ? -inf : (Q.K^T)/sqrt(D)); rowsum atomics -------
__global__ __launch_bounds__(256) void scores_kernel(const f16* __restrict__ Q,
                                                     const f16* __restrict__ Kh,
                                                     const int* __restrict__ mask,
                                                     float* __restrict__ E,
                                                     float* __restrict__ rowsum) {
  __shared__ f16 As[128 * 32];
  __shared__ f16 Bs[128 * 32];
  int t = threadIdx.x;
  int m0 = blockIdx.y * 128, n0 = blockIdx.x * 128;
  int lane = t & 63, wv = t >> 6, quad = lane >> 4, l15 = lane & 15;
  int m_off = (wv & 1) * 64, n_off = (wv >> 1) * 64;
  f32x4 acc[4][4] = {};
  for (int kt = 0; kt < DMODEL; kt += 32) {
    __syncthreads();
    stage128x32(Q, m0, kt, DMODEL, As, t);
    stage128x32(Kh, n0, kt, DMODEL, Bs, t);
    __syncthreads();
    f16x8 af[4], bf[4];
    const f16x8* Av = (const f16x8*)As;
    const f16x8* Bv = (const f16x8*)Bs;
#pragma unroll
    for (int mt = 0; mt < 4; ++mt) af[mt] = Av[(m_off + mt * 16 + l15) * 4 + quad];
#pragma unroll
    for (int nt = 0; nt < 4; ++nt) bf[nt] = Bv[(n_off + nt * 16 + l15) * 4 + quad];
#pragma unroll
    for (int mt = 0; mt < 4; ++mt)
#pragma unroll
      for (int nt = 0; nt < 4; ++nt)
        acc[mt][nt] = __builtin_amdgcn_mfma_f32_16x16x32_f16(af[mt], bf[nt], acc[mt][nt], 0, 0, 0);
  }
  const float scale = 0.044194173824159216f;  // 1/sqrt(512)
#pragma unroll
  for (int mt = 0; mt < 4; ++mt)
#pragma unroll
    for (int r = 0; r < 4; ++r) {
      int row = m0 + m_off + mt * 16 + quad * 4 + r;
      float rs = 0.f;
#pragma unroll
      for (int nt = 0; nt < 4; ++nt) {
        int col = n0 + n_off + nt * 16 + l15;
        size_t idx = (size_t)row * NTOK + col;
        float s = acc[mt][nt][r] * scale;
        float e = mask[idx] ? 0.f : __expf(s);
        E[idx] = e;
        rs += e;
      }
      rs += __shfl_xor(rs, 1);
      rs += __shfl_xor(rs, 2);
      rs += __shfl_xor(rs, 4);
      rs += __shfl_xor(rs, 8);
      if (l15 == 0) atomicAdd(&rowsum[row], rs);
    }
}

// ------- normalize attn in place + cntx = attn @ V (K-chunked, atomic acc) -------
__global__ __launch_bounds__(512, 2) void norm_ev(float* __restrict__ E,
                                                  const float* __restrict__ rowsum,
                                                  const f16* __restrict__ Vt,
                                                  float* __restrict__ cntx) {
  __shared__ f16 Es[128 * 32];  // 8 KB
  __shared__ f16 Vs[512 * 32];  // 32 KB
  int t = threadIdx.x;
  int r0 = blockIdx.x * 128;
  int k0 = blockIdx.y * 2048;
  int lane = t & 63, wv = t >> 6, quad = lane >> 4, l15 = lane & 15;
  int m_off = (wv & 1) * 64, n_off = (wv >> 1) * 128;
  int srow = t >> 3, scol = (t & 7) * 4;
  float rinv0 = 1.f / rowsum[r0 + srow];
  float rinv1 = 1.f / rowsum[r0 + srow + 64];
  f32x4 acc[4][8] = {};
  for (int kt = k0; kt < k0 + 2048; kt += 32) {
    __syncthreads();
    {  // stage E tile: read fp32, normalize, write back (final attn), cvt f16 -> LDS
      size_t g = (size_t)(r0 + srow) * NTOK + kt + scol;
      float4 v = *(const float4*)(E + g);
      v.x *= rinv0; v.y *= rinv0; v.z *= rinv0; v.w *= rinv0;
      *(float4*)(E + g) = v;
      f16x4 h; h.x = (f16)v.x; h.y = (f16)v.y; h.z = (f16)v.z; h.w = (f16)v.w;
      *(f16x4*)(Es + srow * 32 + scol) = h;
      size_t g2 = g + (size_t)64 * NTOK;
      float4 v2 = *(const float4*)(E + g2);
      v2.x *= rinv1; v2.y *= rinv1; v2.z *= rinv1; v2.w *= rinv1;
      *(float4*)(E + g2) = v2;
      f16x4 h2; h2.x = (f16)v2.x; h2.y = (f16)v2.y; h2.z = (f16)v2.z; h2.w = (f16)v2.w;
      *(f16x4*)(Es + (srow + 64) * 32 + scol) = h2;
    }
#pragma unroll
    for (int i = 0; i < 4; ++i) {  // stage V tile [512 d x 32 k] from Vt
      const f16* g = Vt + (size_t)((i * 512 + t) >> 2) * NTOK + kt + (t & 3) * 8;
      async_ld16(g, (char*)Vs + i * 8192 + wv * 1024);
    }
    __syncthreads();
    f16x8 af[4], bf[8];
    const f16x8* Ev = (const f16x8*)Es;
    const f16x8* Vv = (const f16x8*)Vs;
#pragma unroll
    for (int mt = 0; mt < 4; ++mt) af[mt] = Ev[(m_off + mt * 16 + l15) * 4 + quad];
#pragma unroll
    for (int nt = 0; nt < 8; ++nt) bf[nt] = Vv[(n_off + nt * 16 + l15) * 4 + quad];
#pragma unroll
    for (int mt = 0; mt < 4; ++mt)
#pragma unroll
      for (int nt = 0; nt < 8; ++nt)
        acc[mt][nt] = __builtin_amdgcn_mfma_f32_16x16x32_f16(af[mt], bf[nt], acc[mt][nt], 0, 0, 0);
  }
#pragma unroll
  for (int mt = 0; mt < 4; ++mt)
#pragma unroll
    for (int nt = 0; nt < 8; ++nt)
#pragma unroll
      for (int r = 0; r < 4; ++r) {
        int row = r0 + m_off + mt * 16 + quad * 4 + r;
        int col = n_off + nt * 16 + l15;
        atomicAdd(&cntx[(size_t)row * DMODEL + col], acc[mt][nt][r]);
      }
}

extern "C" void kernel_launch(void* const* d_in, const int* in_sizes, int n_in,
                              void* d_out, int out_size, void* d_ws, size_t ws_size,
                              hipStream_t stream) {
  const float* x  = (const float*)d_in[0];
  const int* mask = (const int*)d_in[1];
  const float* Wq = (const float*)d_in[2];
  const float* Wk = (const float*)d_in[3];
  const float* Wv = (const float*)d_in[4];
  float* cntx = (float*)d_out;
  float* attn = (float*)d_out + (size_t)NTOK * DMODEL;

  // workspace layout (f16): xh 8MB | Wh 1.5MB | Q,K,V 24MB | Vt 8MB | rowsum 32KB
  f16* xh = (f16*)d_ws;
  f16* Wh = xh + (size_t)NTOK * DMODEL;
  f16* QKV = Wh + (size_t)3 * DMODEL * DMODEL;
  f16* Qh = QKV;
  f16* Kh = QKV + (size_t)NTOK * DMODEL;
  f16* Vh = QKV + (size_t)2 * NTOK * DMODEL;
  f16* Vt = QKV + (size_t)3 * NTOK * DMODEL;
  float* rowsum = (float*)(Vt + (size_t)NTOK * DMODEL);

  hipMemsetAsync(cntx, 0, (size_t)NTOK * DMODEL * sizeof(float), stream);
  hipMemsetAsync(rowsum, 0, NTOK * sizeof(float), stream);

  pack_f16<<<dim3(NTOK * DMODEL / 1024), 256, 0, stream>>>(x, xh, NTOK * DMODEL);
  pack_f16<<<dim3(DMODEL * DMODEL / 1024), 256, 0, stream>>>(Wq, Wh, DMODEL * DMODEL);
  pack_f16<<<dim3(DMODEL * DMODEL / 1024), 256, 0, stream>>>(Wk, Wh + DMODEL * DMODEL, DMODEL * DMODEL);
  pack_f16<<<dim3(DMODEL * DMODEL / 1024), 256, 0, stream>>>(Wv, Wh + 2 * DMODEL * DMODEL, DMODEL * DMODEL);

  qkv_gemm<<<dim3(DMODEL / 128, NTOK / 128, 3), 256, 0, stream>>>(xh, Wh, QKV);
  transpose_f16<<<dim3(NTOK / 64, DMODEL / 64), 256, 0, stream>>>(Vh, Vt);
  scores_kernel<<<dim3(NTOK / 128, NTOK / 128), 256, 0, stream>>>(Qh, Kh, mask, attn, rowsum);
  norm_ev<<<dim3(NTOK / 128, 4), 512, 0, stream>>>(attn, rowsum, Vt, cntx);
}